// Round 5
// 554.225 us; speedup vs baseline: 1.0461x; 1.0461x over previous
//
#include <hip/hip_runtime.h>
#include <math.h>

// Problem constants (B=10240, D=512, M=8, L=3)
#define BB   10240
#define DD   512
#define MM   8

typedef _Float16 h8 __attribute__((ext_vector_type(8)));
typedef float    f4 __attribute__((ext_vector_type(4)));

// async global->LDS DMA, 16 B per lane; LDS dst = wave-uniform base + lane*16
__device__ __forceinline__ void gload16(const void* g, void* l) {
    __builtin_amdgcn_global_load_lds(
        (__attribute__((address_space(1))) void*)(g),
        (__attribute__((address_space(3))) void*)(l), 16, 0, 0);
}

// ---------------- fp32 -> fp16 convert (8 elems/thread) ----------------
__global__ void __launch_bounds__(256) cvt_f32_f16(const float* __restrict__ s,
                                                   _Float16* __restrict__ d, int n8) {
    int i = blockIdx.x * 256 + threadIdx.x;
    if (i >= n8) return;
    const float4* sp = (const float4*)s + (size_t)i * 2;
    float4 a = sp[0], b = sp[1];
    h8 o = { (_Float16)a.x, (_Float16)a.y, (_Float16)a.z, (_Float16)a.w,
             (_Float16)b.x, (_Float16)b.y, (_Float16)b.z, (_Float16)b.w };
    *(h8*)(d + (size_t)i * 8) = o;
}

// ---------------- fused layer GEMM ----------------
// C[b,i] = gW[b,i] * sum_m pW[b,m] sum_j W[m,i,j] x[b,j]  +  gb[b,i]*sum_m pb[b,m]*bs[m,i]
//
// Counted-vmcnt pipeline (T3+T4): raw s_barrier (no vmcnt(0) drain) + per-step
// s_waitcnt vmcnt(N).  W tiles: 4-buffer ring, staged 3 steps ahead (~600+ cyc
// window, L2-resident per XCD).  A tiles: 2 buffers, staged 7 steps ahead
// (covers HBM latency).  FIFO accounting: steady N=6 (3 W-stages x 2 loads in
// flight), N=10 when the 4-load A stage is inside the window (mi in 1..4);
// tail drains 6,6,6,6,6,4,2,0.  setprio(1) wraps the MFMA cluster (T5).
// XOR-swizzled LDS (16B chunk ^ row) unchanged -> 0 bank conflicts.
template <int HALF_OUT>
__global__ void __launch_bounds__(256) gemm_layer(
    const _Float16* __restrict__ xh,   // (B,512) fp16
    const _Float16* __restrict__ Wh,   // (8,512,512) fp16
    const float*  __restrict__ pW,     // (B,8)
    const float*  __restrict__ pb,     // (B,8)
    const float*  __restrict__ bsv,    // (8,512)
    const float*  __restrict__ gW,     // (B,512)
    const float*  __restrict__ gb,     // (B,512)
    float* __restrict__ outf,          // (B,512) fp32 (final layer)
    _Float16* __restrict__ outh)       // (B,512) fp16 (hidden layers)
{
    __shared__ __align__(16) _Float16 Abuf[2][128 * 64];  // 2 x 16 KB
    __shared__ __align__(16) _Float16 Wbuf[4][64 * 64];   // 4 x  8 KB  (ring)

    const int tid  = threadIdx.x;
    const int lane = tid & 63;
    const int w    = tid >> 6;
    const int wm   = w >> 1, wn = w & 1;
    const int ln16 = lane & 15, quad = lane >> 4;
    const int bn0  = blockIdx.x * 64;
    const int bm0  = blockIdx.y * 128;

    // per-lane pW for this wave's 4 A-row groups, all 8 m, as fp16
    _Float16 pwh[4][8];
    #pragma unroll
    for (int mt = 0; mt < 4; ++mt) {
        const float* pp = pW + (size_t)(bm0 + wm * 64 + mt * 16 + ln16) * MM;
        float4 p0 = *(const float4*)pp;
        float4 p1 = *(const float4*)(pp + 4);
        pwh[mt][0] = (_Float16)p0.x; pwh[mt][1] = (_Float16)p0.y;
        pwh[mt][2] = (_Float16)p0.z; pwh[mt][3] = (_Float16)p0.w;
        pwh[mt][4] = (_Float16)p1.x; pwh[mt][5] = (_Float16)p1.y;
        pwh[mt][6] = (_Float16)p1.z; pwh[mt][7] = (_Float16)p1.w;
    }

    // --- DMA staging: contiguous per-wave 1 KB chunks; XOR swizzle applied
    //     on the GLOBAL side so LDS-phys chunk p of row r holds logical p^r. ---
    auto stageA = [&](int buf, int jc) {           // 4 vmcnt slots
        #pragma unroll
        for (int c = 0; c < 4; ++c) {
            int rbase   = w * 32 + c * 8;
            int row     = rbase + (lane >> 3);
            int logical = (lane & 7) ^ (row & 7);
            const _Float16* gp = xh + (size_t)(bm0 + row) * DD + jc * 64 + logical * 8;
            gload16(gp, &Abuf[buf][rbase * 64]);
        }
    };
    auto stageW = [&](int buf, int m, int jc) {    // 2 vmcnt slots
        #pragma unroll
        for (int c = 0; c < 2; ++c) {
            int rbase   = w * 16 + c * 8;
            int row     = rbase + (lane >> 3);
            int logical = (lane & 7) ^ (row & 7);
            const _Float16* gp = Wh + (size_t)m * (DD * DD)
                                    + (size_t)(bn0 + row) * DD + jc * 64 + logical * 8;
            gload16(gp, &Wbuf[buf][rbase * 64]);
        }
    };

    f4 acc[4][2] = {};
    h8 af[2][4];   // [ks][mt] A fragments, live across the m loop

    // prologue: A(jc=0) + W tiles t=0,1,2 in flight
    stageA(0, 0);
    stageW(0, 0, 0);
    stageW(1, 1, 0);
    stageW(2, 2, 0);

// One pipeline step (tile t = jc*8 + MI, W tile (m=MI, jc) read from Wbuf[MI&3]).
// Issues W(t+3) into Wbuf[(MI+3)&3] and (at MI==1) A(jc+1); waits vmcnt(NVM)
// (own W(t) loads landed), barrier #1 publishes the tile; ds_read + MFMA;
// barrier #2 protects Wbuf[MI&3] from next step's overwrite.
#define GSTEP(MI, NVM, DO_STW, SM, SJ, DO_STA) do {                           \
    if (DO_STW) stageW(((MI) + 3) & 3, (SM), (SJ));                            \
    if (DO_STA) stageA((jc + 1) & 1, jc + 1);                                  \
    asm volatile("s_waitcnt vmcnt(%0)" :: "i"(NVM) : "memory");                \
    __builtin_amdgcn_s_barrier();                                              \
    asm volatile("" ::: "memory");                                             \
    if ((MI) == 0) {                                                           \
        _Pragma("unroll")                                                      \
        for (int ks = 0; ks < 2; ++ks) {                                       \
            _Pragma("unroll")                                                  \
            for (int mt = 0; mt < 4; ++mt) {                                   \
                int row  = wm * 64 + mt * 16 + ln16;                           \
                int phys = (ks * 4 + quad) ^ (row & 7);                        \
                af[ks][mt] = *(const h8*)&Abuf[jc & 1][row * 64 + phys * 8];   \
            }                                                                  \
        }                                                                      \
    }                                                                          \
    h8 bfr[2][2];                                                              \
    _Pragma("unroll")                                                          \
    for (int ks = 0; ks < 2; ++ks) {                                           \
        _Pragma("unroll")                                                      \
        for (int nt = 0; nt < 2; ++nt) {                                       \
            int row  = wn * 32 + nt * 16 + ln16;                               \
            int phys = (ks * 4 + quad) ^ (row & 7);                            \
            bfr[ks][nt] = *(const h8*)&Wbuf[(MI) & 3][row * 64 + phys * 8];    \
        }                                                                      \
    }                                                                          \
    __builtin_amdgcn_s_setprio(1);                                             \
    _Pragma("unroll")                                                          \
    for (int ks = 0; ks < 2; ++ks) {                                           \
        _Pragma("unroll")                                                      \
        for (int mt = 0; mt < 4; ++mt) {                                       \
            h8 as = af[ks][mt] * pwh[mt][(MI)];   /* v_pk_mul_f16 x4 */        \
            _Pragma("unroll")                                                  \
            for (int nt = 0; nt < 2; ++nt)                                     \
                acc[mt][nt] = __builtin_amdgcn_mfma_f32_16x16x32_f16(          \
                    as, bfr[ks][nt], acc[mt][nt], 0, 0, 0);                    \
        }                                                                      \
    }                                                                          \
    __builtin_amdgcn_s_setprio(0);                                             \
    __builtin_amdgcn_s_barrier();                                              \
    asm volatile("" ::: "memory");                                             \
} while (0)

    for (int jc = 0; jc < 7; ++jc) {
        GSTEP(0,  6, 1, 3, jc,     0);
        GSTEP(1, 10, 1, 4, jc,     1);   // A(jc+1) issued here: 7-step window
        GSTEP(2, 10, 1, 5, jc,     0);
        GSTEP(3, 10, 1, 6, jc,     0);
        GSTEP(4, 10, 1, 7, jc,     0);
        GSTEP(5,  6, 1, 0, jc + 1, 0);
        GSTEP(6,  6, 1, 1, jc + 1, 0);
        GSTEP(7,  6, 1, 2, jc + 1, 0);
    }
    {   // final jc = 7: no more A stages; W ring drains 6,6,6,6,6,4,2,0
        const int jc = 7;
        GSTEP(0, 6, 1, 3, 7, 0);
        GSTEP(1, 6, 1, 4, 7, 0);
        GSTEP(2, 6, 1, 5, 7, 0);
        GSTEP(3, 6, 1, 6, 7, 0);
        GSTEP(4, 6, 1, 7, 7, 0);
        GSTEP(5, 4, 0, 0, 0, 0);
        GSTEP(6, 2, 0, 0, 0, 0);
        GSTEP(7, 0, 0, 0, 0, 0);
    }
#undef GSTEP

    // ---- epilogue: out = gW*acc + gb*(sum_m pb*bs) ----
    const int i0 = bn0 + wn * 32 + ln16;
    const int i1 = i0 + 16;
    float bs0[8], bs1[8];
    #pragma unroll
    for (int m2 = 0; m2 < 8; ++m2) {
        bs0[m2] = bsv[m2 * DD + i0];
        bs1[m2] = bsv[m2 * DD + i1];
    }
    #pragma unroll
    for (int mt = 0; mt < 4; ++mt) {
        #pragma unroll
        for (int r = 0; r < 4; ++r) {
            int b = bm0 + wm * 64 + mt * 16 + quad * 4 + r;
            float4 p0 = *(const float4*)(pb + (size_t)b * MM);
            float4 p1 = *(const float4*)(pb + (size_t)b * MM + 4);
            float bias0 = p0.x*bs0[0] + p0.y*bs0[1] + p0.z*bs0[2] + p0.w*bs0[3]
                        + p1.x*bs0[4] + p1.y*bs0[5] + p1.z*bs0[6] + p1.w*bs0[7];
            float bias1 = p0.x*bs1[0] + p0.y*bs1[1] + p0.z*bs1[2] + p0.w*bs1[3]
                        + p1.x*bs1[4] + p1.y*bs1[5] + p1.z*bs1[6] + p1.w*bs1[7];
            float v0 = gW[(size_t)b * DD + i0] * acc[mt][0][r] + gb[(size_t)b * DD + i0] * bias0;
            float v1 = gW[(size_t)b * DD + i1] * acc[mt][1][r] + gb[(size_t)b * DD + i1] * bias1;
            if (HALF_OUT) {
                outh[(size_t)b * DD + i0] = (_Float16)v0;
                outh[(size_t)b * DD + i1] = (_Float16)v1;
            } else {
                outf[(size_t)b * DD + i0] = v0;
                outf[(size_t)b * DD + i1] = v1;
            }
        }
    }
}

// ---------------- LayerNorm (no affine) + ELU, fp16 in/out ----------------
__global__ void __launch_bounds__(256) ln_elu_h(const _Float16* __restrict__ h,
                                                _Float16* __restrict__ xo) {
    const int w    = threadIdx.x >> 6;
    const int lane = threadIdx.x & 63;
    const int row  = blockIdx.x * 4 + w;
    h8 v = *(const h8*)(h + (size_t)row * DD + lane * 8);
    float f[8], s = 0.f, q = 0.f;
    #pragma unroll
    for (int i = 0; i < 8; ++i) { f[i] = (float)v[i]; s += f[i]; q += f[i] * f[i]; }
    #pragma unroll
    for (int off = 1; off < 64; off <<= 1) {
        s += __shfl_xor(s, off);
        q += __shfl_xor(q, off);
    }
    float mu   = s * (1.0f / 512.0f);
    float var  = q * (1.0f / 512.0f) - mu * mu;
    float rstd = rsqrtf(var + 1e-5f);
    h8 o;
    #pragma unroll
    for (int i = 0; i < 8; ++i) {
        float t = (f[i] - mu) * rstd;
        t = t > 0.0f ? t : expm1f(t);
        o[i] = (_Float16)t;
    }
    *(h8*)(xo + (size_t)row * DD + lane * 8) = o;
}

extern "C" void kernel_launch(void* const* d_in, const int* in_sizes, int n_in,
                              void* d_out, int out_size, void* d_ws, size_t ws_size,
                              hipStream_t stream) {
    const float* x   = (const float*)d_in[0];   // (B,512)
    const float* Ws  = (const float*)d_in[1];   // (3,8,512,512)
    const float* bs  = (const float*)d_in[2];   // (3,8,512)
    const float* pWs = (const float*)d_in[3];   // (3,B,8)
    const float* pbs = (const float*)d_in[4];   // (3,B,8)
    const float* gWs = (const float*)d_in[5];   // (3,B,512,1)
    const float* gbs = (const float*)d_in[6];   // (3,B,512)
    float* out = (float*)d_out;

    // workspace: Wh 12.58 MB + xh 10.49 MB + hh 10.49 MB = 32 MiB exactly
    _Float16* Wh = (_Float16*)d_ws;
    _Float16* xh = Wh + (size_t)3 * MM * DD * DD;
    _Float16* hh = xh + (size_t)BB * DD;

    const int wsl = MM * DD * DD;        // per-layer W elems
    const int bsl = MM * DD;
    const int pl  = BB * MM;
    const int gl  = BB * DD;

    cvt_f32_f16<<<3072, 256, 0, stream>>>(Ws, Wh, 786432);   // 3*8*512*512/8
    cvt_f32_f16<<<2560, 256, 0, stream>>>(x, xh, 655360);    // B*512/8

    dim3 gg(DD / 64, BB / 128);          // (8, 80)

    // layer 0
    gemm_layer<1><<<gg, 256, 0, stream>>>(xh, Wh, pWs, pbs, bs, gWs, gbs,
                                          nullptr, hh);
    ln_elu_h<<<BB / 4, 256, 0, stream>>>(hh, xh);
    // layer 1
    gemm_layer<1><<<gg, 256, 0, stream>>>(xh, Wh + wsl, pWs + pl, pbs + pl,
                                          bs + bsl, gWs + gl, gbs + gl,
                                          nullptr, hh);
    ln_elu_h<<<BB / 4, 256, 0, stream>>>(hh, xh);
    // layer 2 (no LN, fp32 out)
    gemm_layer<0><<<gg, 256, 0, stream>>>(xh, Wh + 2 * wsl, pWs + 2 * pl,
                                          pbs + 2 * pl, bs + 2 * bsl,
                                          gWs + 2 * gl, gbs + 2 * gl,
                                          out, nullptr);
}